// Round 14
// baseline (112.388 us; speedup 1.0000x reference)
//
#include <hip/hip_runtime.h>
#include <hip/hip_bf16.h>

typedef __bf16 bf16x8 __attribute__((ext_vector_type(8)));
typedef __bf16 bf16x4 __attribute__((ext_vector_type(4)));
typedef float  f32x4  __attribute__((ext_vector_type(4)));
typedef float  f4v    __attribute__((ext_vector_type(4)));

#define DEV __device__ __forceinline__

DEV void gload16(void* lds, const void* g) {
    __builtin_amdgcn_global_load_lds((const __attribute__((address_space(1))) void*)g,
                                     (__attribute__((address_space(3))) void*)lds, 16, 0, 0);
}

#define VMCNT(n) asm volatile("s_waitcnt vmcnt(" #n ")" ::: "memory")
#define LGKM0()  asm volatile("s_waitcnt lgkmcnt(0)" ::: "memory")
#define BAR()    __builtin_amdgcn_s_barrier()
#define BARM()   asm volatile("s_barrier" ::: "memory")
#define SCHEDB() __builtin_amdgcn_sched_barrier(0)

// ---------------- fused prepass: cvt(hid) | transpose(Wqkv) | transpose(Wproj) | cs tables ----------------
__global__ __launch_bounds__(256) void k_prep(const float* __restrict__ hid, __bf16* __restrict__ hb,
                                              const float* __restrict__ Wqkv, __bf16* __restrict__ WqT,
                                              const float* __restrict__ Wproj, __bf16* __restrict__ WpT,
                                              const float* __restrict__ rcos, const float* __restrict__ rsin,
                                              __bf16* __restrict__ csb, __bf16* __restrict__ snb) {
    __shared__ float tile[64][65];
    const int b = blockIdx.x;
    const int tid = threadIdx.x;

    if (b < 5120) {
        int i = b * 256 + tid;
        f4v v = ((const f4v*)hid)[i];
        bf16x4 o;
        #pragma unroll
        for (int j = 0; j < 4; ++j) o[j] = (__bf16)v[j];
        ((bf16x4*)hb)[i] = o;
        return;
    }
    if (b < 5120 + 1200 + 400) {
        const float* in;
        __bf16* out;
        int R, C, bb, cb;
        if (b < 5120 + 1200) { in = Wqkv; out = WqT; R = 1280; C = 3840; cb = 60; bb = b - 5120; }
        else                 { in = Wproj; out = WpT; R = 1280; C = 1280; cb = 20; bb = b - 6320; }
        int br = (bb / cb) * 64, bc = (bb % cb) * 64;
        int tx = tid & 63, ty = tid >> 6;
        #pragma unroll
        for (int i = 0; i < 16; ++i) {
            int r = i * 4 + ty;
            tile[r][tx] = in[(size_t)(br + r) * C + (bc + tx)];
        }
        __syncthreads();
        #pragma unroll
        for (int i = 0; i < 16; ++i) {
            int r = i * 4 + ty;
            out[(size_t)(bc + r) * R + (br + tx)] = (__bf16)tile[tx][r];
        }
        return;
    }
    {
        int i = (b - 6720) * 256 + tid;
        f4v cv = ((const f4v*)rcos)[i];
        f4v sv = ((const f4v*)rsin)[i];
        bf16x4 co, so;
        #pragma unroll
        for (int j = 0; j < 4; ++j) { co[j] = (__bf16)cv[j]; so[j] = (__bf16)sv[j]; }
        ((bf16x4*)csb)[i] = co;
        ((bf16x4*)snb)[i] = so;
    }
}

// ---------------- 4-deep pipelined GEMM (T4: counted vmcnt, loads in flight across barriers) ----------------
// BK=32. LDS: 4 buffers of (BM+BN) rows x 32 elems. Row = 4 slots of 8 elems;
// physical slot for logical k-group g at row r: slot = (g + r + (r>>2)) & 3
// (additive permute; stage source pre-applies the inverse). B stored [N][K].
// Per tile: {vmcnt(4); barrier; stage(t+2); ds_read frags; MFMA} -- stage(t+1)
// never drained in-loop.
template<int BM, int BN, int WM, int WN, int OUTF32, int VOUT>
__global__ __launch_bounds__(WM * WN * 64, 2)
void k_gemm4(const __bf16* __restrict__ A,
             const __bf16* __restrict__ B,
             const float* __restrict__ bias,
             void* __restrict__ Cp,
             __bf16* __restrict__ Vt,
             int M, int N, int K) {
    constexpr int T   = WM * WN * 64;
    constexpr int WTM = BM / WM, WTN = BN / WN;
    constexpr int AM  = WTM / 16, AN = WTN / 16;
    constexpr int LR  = BM + BN;
    constexpr int BUFE = LR * 32;          // elems per buffer
    constexpr int LP  = (LR * 4) / T;      // stage loads per thread
    static_assert(LP == 4, "expect 4 stage loads per thread");

    __shared__ __align__(16) __bf16 lds[4 * BUFE];
    const int tid = threadIdx.x;
    const int lane = tid & 63, w = tid >> 6;
    const int wm = w / WN, wn = w % WN;
    const int g = lane >> 4, fr = lane & 15;

    const int nbn = N / BN;
    const int nwg = gridDim.x;
    int bid = blockIdx.x;
    {   // bijective XCD swizzle
        int q = nwg >> 3, r = nwg & 7;
        int xcd = bid & 7, o = bid >> 3;
        bid = (xcd < r ? xcd * (q + 1) : r * (q + 1) + (xcd - r) * q) + o;
    }
    const int bm = bid / nbn, bn = bid % nbn;
    const int brow = bm * BM, bcol = bn * BN;

    // staging geometry: unit u = p*T + tid -> row u>>2, slot u&3 (= tid&3)
    const __bf16* gp[LP];
    #pragma unroll
    for (int p = 0; p < LP; ++p) {
        const int row = (p * T + tid) >> 2;
        const int slot = tid & 3;
        const int srccol = ((slot - row - (row >> 2)) & 3) << 3;  // inverse permute
        gp[p] = (row < BM) ? (A + (size_t)(brow + row) * K + srccol)
                           : (B + (size_t)(bcol + (row - BM)) * K + srccol);
    }
    __bf16* ldst = &lds[0] + tid * 8;

    #define STAGE(bufsel, kt)                                                        \
        {                                                                            \
            _Pragma("unroll")                                                        \
            for (int p = 0; p < LP; ++p)                                             \
                gload16(ldst + (bufsel) * BUFE + p * (T * 8), gp[p] + (kt) * 32);    \
        }

    const int NT = K >> 5;
    f32x4 acc[AM][AN] = {};

    STAGE(0, 0);
    STAGE(1, 1);

    for (int t = 0; t < NT; ++t) {
        if (t + 1 < NT) { VMCNT(4); } else { VMCNT(0); }
        BARM();
        if (t + 2 < NT) STAGE((t + 2) & 3, t + 2);

        const __bf16* buf = &lds[(t & 3) * BUFE];
        bf16x8 a[AM], b[AN];
        #pragma unroll
        for (int m = 0; m < AM; ++m) {
            const int row = wm * WTM + m * 16 + fr;
            const int slot = (g + row + (row >> 2)) & 3;
            a[m] = *(const bf16x8*)__builtin_assume_aligned(&buf[row * 32 + slot * 8], 16);
        }
        #pragma unroll
        for (int n = 0; n < AN; ++n) {
            const int row = BM + wn * WTN + n * 16 + fr;
            const int slot = (g + row + (row >> 2)) & 3;
            b[n] = *(const bf16x8*)__builtin_assume_aligned(&buf[row * 32 + slot * 8], 16);
        }
        __builtin_amdgcn_s_setprio(1);
        #pragma unroll
        for (int m = 0; m < AM; ++m)
            #pragma unroll
            for (int n = 0; n < AN; ++n)
                acc[m][n] = __builtin_amdgcn_mfma_f32_16x16x32_bf16(a[m], b[n], acc[m][n], 0, 0, 0);
        __builtin_amdgcn_s_setprio(0);
    }
    #undef STAGE

    #pragma unroll
    for (int n = 0; n < AN; ++n) {
        const int col = bcol + wn * WTN + n * 16 + fr;
        const float bv = bias[col];
        if (VOUT && col >= 2560) {
            const int vcol = col - 2560;
            const int hh = vcol / 80;
            const int dd = vcol - hh * 80;
            __bf16* vp = Vt + (size_t)(hh * 80 + dd) * 4096 + brow + wm * WTM + g * 4;
            #pragma unroll
            for (int m = 0; m < AM; ++m) {
                bf16x4 pk;
                #pragma unroll
                for (int j = 0; j < 4; ++j) pk[j] = (__bf16)(acc[m][n][j] + bv);
                *(bf16x4*)(vp + m * 16) = pk;
            }
        } else {
            #pragma unroll
            for (int m = 0; m < AM; ++m) {
                const int row = brow + wm * WTM + m * 16 + g * 4;
                #pragma unroll
                for (int j = 0; j < 4; ++j) {
                    float v = acc[m][n][j] + bv;
                    if (OUTF32) ((float*)Cp)[(size_t)(row + j) * N + col] = v;
                    else        ((__bf16*)Cp)[(size_t)(row + j) * N + col] = (__bf16)v;
                }
            }
        }
    }
}

// ---------------- flash attention: QBLK=256, dbuf + async reg-stage, FUSED K-RoPE, in-reg L ----------------
__global__ __launch_bounds__(512, 2) void k_attn(const __bf16* __restrict__ qkv,
                                                 const __bf16* __restrict__ csb,
                                                 const __bf16* __restrict__ snb,
                                                 const __bf16* __restrict__ Vt,
                                                 __bf16* __restrict__ Ao) {
    __shared__ __align__(16) __bf16 Ks[2][3 * 2048];
    __shared__ __align__(16) __bf16 Vs[2][96 * 64];
    __shared__ __align__(16) __bf16 Pl[8 * 1024];

    const int blk = blockIdx.x;
    const int seg = blk & 7;
    const int qt = (blk >> 3) & 1;
    const int h = blk >> 4;
    const int tid = threadIdx.x;
    const int w = tid >> 6, lane = tid & 63;
    const int g = lane >> 4, fr = lane & 15;
    const int qrow0 = seg * 512 + qt * 256 + w * 32;
    const float qscale = 0.111803398875f * 1.44269504089f; // rsqrt(80) * log2(e)

    const int krow = tid / 5, ksl = tid - krow * 5;   // valid when tid < 320
    const int kd = ksl * 8;
    const int vd0 = tid >> 3, vc0 = (tid & 7) << 3;
    const int vd1 = 64 + (tid >> 3);
    const __bf16* kqbase = qkv + 1280 + h * 80;
    const __bf16* vbase = Vt + (size_t)h * 80 * 4096;

    bf16x8 kx1, kx2, kcs, ksn, vA, vB;
    {
        const int s = seg * 512 + krow;
        if (tid < 320) {
            kx1 = *(const bf16x8*)(kqbase + (size_t)s * 3840 + kd);
            kx2 = *(const bf16x8*)(kqbase + (size_t)s * 3840 + kd + 40);
            kcs = *(const bf16x8*)(csb + s * 40 + kd);
            ksn = *(const bf16x8*)(snb + s * 40 + kd);
        }
        const int t0 = seg * 512;
        vA = *(const bf16x8*)(vbase + (size_t)vd0 * 4096 + t0 + vc0);
        if (tid < 128) vB = *(const bf16x8*)(vbase + (size_t)vd1 * 4096 + t0 + vc0);
    }
    SCHEDB();

    bf16x8 aq[2][3];
    #pragma unroll
    for (int rg = 0; rg < 2; ++rg) {
        const int s = qrow0 + rg * 16 + fr;
        const __bf16* qrow = qkv + (size_t)s * 3840 + h * 80;
        const __bf16* cr = csb + s * 40;
        const __bf16* sr2 = snb + s * 40;
        #pragma unroll
        for (int ks = 0; ks < 3; ++ks) {
            const int cc0 = ks * 32 + g * 8;
            bf16x8 v;
            if (cc0 < 80) {
                const int lo = (cc0 < 40) ? 1 : 0;
                const int d0 = lo ? cc0 : cc0 - 40;
                bf16x8 x = *(const bf16x8*)(qrow + cc0);
                bf16x8 y = *(const bf16x8*)(qrow + (lo ? cc0 + 40 : cc0 - 40));
                bf16x8 cv = *(const bf16x8*)(cr + d0);
                bf16x8 sv = *(const bf16x8*)(sr2 + d0);
                #pragma unroll
                for (int j = 0; j < 8; ++j) {
                    float xf = (float)x[j], yf = (float)y[j];
                    float cf = (float)cv[j], sf = (float)sv[j];
                    float r = lo ? (xf * cf - yf * sf) : (xf * cf + yf * sf);
                    v[j] = (__bf16)(r * qscale);
                }
            } else {
                #pragma unroll
                for (int j = 0; j < 8; ++j) v[j] = (__bf16)0.f;
            }
            aq[rg][ks] = v;
        }
    }

    // zero cols 80..95 of BOTH Ks buffers once (staging writes only cols 0..79 images)
    if (tid < 256) {
        const int buf = tid >> 7;
        const int rr = (tid >> 1) & 63;
        const int cc = 80 + ((tid & 1) << 3);
        bf16x8 z;
        #pragma unroll
        for (int j = 0; j < 8; ++j) z[j] = (__bf16)0.f;
        *(bf16x8*)&Ks[buf][2 * 2048 + rr * 32 + ((cc & 31) ^ ((rr & 3) << 3))] = z;
    }

    f32x4 o[2][5] = {};
    float Lacc[2] = {0.f, 0.f};
    __bf16* pw = &Pl[w * 1024];

    for (int tc = 0; tc < 8; ++tc) {
        const int p = tc & 1;

        VMCNT(0);
        if (tid < 320) {
            bf16x8 o1, o2;
            #pragma unroll
            for (int j = 0; j < 8; ++j) {
                float x1 = (float)kx1[j], x2 = (float)kx2[j];
                float cf = (float)kcs[j], sf = (float)ksn[j];
                o1[j] = (__bf16)(x1 * cf - x2 * sf);
                o2[j] = (__bf16)(x2 * cf + x1 * sf);
            }
            const int c1 = kd, c2 = kd + 40;
            *(bf16x8*)&Ks[p][(c1 >> 5) * 2048 + krow * 32 + ((c1 & 31) ^ ((krow & 3) << 3))] = o1;
            *(bf16x8*)&Ks[p][(c2 >> 5) * 2048 + krow * 32 + ((c2 & 31) ^ ((krow & 3) << 3))] = o2;
        }
        *(bf16x8*)&Vs[p][vd0 * 64 + (vc0 ^ ((vd0 & 7) << 3))] = vA;
        if (tid < 128) *(bf16x8*)&Vs[p][vd1 * 64 + (vc0 ^ ((vd1 & 7) << 3))] = vB;
        LGKM0();
        BAR();

        if (tc + 1 < 8) {
            const int t1 = seg * 512 + (tc + 1) * 64;
            if (tid < 320) {
                const int s = t1 + krow;
                kx1 = *(const bf16x8*)(kqbase + (size_t)s * 3840 + kd);
                kx2 = *(const bf16x8*)(kqbase + (size_t)s * 3840 + kd + 40);
                kcs = *(const bf16x8*)(csb + s * 40 + kd);
                ksn = *(const bf16x8*)(snb + s * 40 + kd);
            }
            vA = *(const bf16x8*)(vbase + (size_t)vd0 * 4096 + t1 + vc0);
            if (tid < 128) vB = *(const bf16x8*)(vbase + (size_t)vd1 * 4096 + t1 + vc0);
            SCHEDB();
        }

        #pragma unroll
        for (int rg = 0; rg < 2; ++rg) {
            f32x4 sacc[4] = {};
            #pragma unroll
            for (int ks = 0; ks < 3; ++ks) {
                #pragma unroll
                for (int n = 0; n < 4; ++n) {
                    bf16x8 bk = *(const bf16x8*)&Ks[p][ks * 2048 + (n * 16 + fr) * 32 + ((g * 8) ^ ((fr & 3) << 3))];
                    sacc[n] = __builtin_amdgcn_mfma_f32_16x16x32_bf16(bk, aq[rg][ks], sacc[n], 0, 0, 0);
                }
            }

            float pv[4][4];
            float rs = 0.f;
            #pragma unroll
            for (int n = 0; n < 4; ++n)
                #pragma unroll
                for (int j = 0; j < 4; ++j) {
                    float e = exp2f(sacc[n][j]);
                    pv[n][j] = e;
                    rs += e;
                }
            rs += __shfl_xor(rs, 16);
            rs += __shfl_xor(rs, 32);
            Lacc[rg] += rs;

            #pragma unroll
            for (int n = 0; n < 4; ++n) {
                bf16x4 pk;
                #pragma unroll
                for (int j = 0; j < 4; ++j) pk[j] = (__bf16)pv[n][j];
                int col = (n * 16 + g * 4) ^ ((fr & 7) << 3);
                *(bf16x4*)&pw[fr * 64 + col] = pk;
            }

            #pragma unroll
            for (int ks2 = 0; ks2 < 2; ++ks2) {
                bf16x8 pa = *(const bf16x8*)&pw[fr * 64 + (((ks2 * 32) + g * 8) ^ ((fr & 7) << 3))];
                #pragma unroll
                for (int dt = 0; dt < 5; ++dt) {
                    bf16x8 bv = *(const bf16x8*)&Vs[p][(dt * 16 + fr) * 64 + (((ks2 * 32) + g * 8) ^ ((fr & 7) << 3))];
                    o[rg][dt] = __builtin_amdgcn_mfma_f32_16x16x32_bf16(pa, bv, o[rg][dt], 0, 0, 0);
                }
            }
        }
    }

    #pragma unroll
    for (int rg = 0; rg < 2; ++rg) {
        float invj[4];
        #pragma unroll
        for (int j = 0; j < 4; ++j)
            invj[j] = 1.0f / __shfl(Lacc[rg], g * 4 + j);
        #pragma unroll
        for (int dt = 0; dt < 5; ++dt)
            #pragma unroll
            for (int j = 0; j < 4; ++j)
                Ao[(size_t)(qrow0 + rg * 16 + g * 4 + j) * 1280 + h * 80 + dt * 16 + fr] =
                    (__bf16)(o[rg][dt][j] * invj[j]);
    }
}

extern "C" void kernel_launch(void* const* d_in, const int* in_sizes, int n_in,
                              void* d_out, int out_size, void* d_ws, size_t ws_size,
                              hipStream_t stream) {
    const float* hid   = (const float*)d_in[0];
    const float* rcos  = (const float*)d_in[3];
    const float* rsin  = (const float*)d_in[4];
    const float* Wqkv  = (const float*)d_in[5];
    const float* bqkv  = (const float*)d_in[6];
    const float* Wproj = (const float*)d_in[7];
    const float* bproj = (const float*)d_in[8];
    float* out = (float*)d_out;

    char* ws = (char*)d_ws;
    size_t off = 0;
    auto carve = [&](size_t bytes) -> char* {
        char* p = ws + off;
        off += (bytes + 255) & ~(size_t)255;
        return p;
    };
    __bf16* hb   = (__bf16*)carve((size_t)4096 * 1280 * 2); // later reused as attn output
    __bf16* WqT  = (__bf16*)carve((size_t)3840 * 1280 * 2);
    __bf16* WpT  = (__bf16*)carve((size_t)1280 * 1280 * 2);
    __bf16* qkvb = (__bf16*)carve((size_t)4096 * 3840 * 2);
    __bf16* Vt   = (__bf16*)carve((size_t)16 * 80 * 4096 * 2);
    __bf16* csb  = (__bf16*)carve((size_t)4096 * 40 * 2);
    __bf16* snb  = (__bf16*)carve((size_t)4096 * 40 * 2);

    k_prep<<<6880, 256, 0, stream>>>(hid, hb, Wqkv, WqT, Wproj, WpT, rcos, rsin, csb, snb);
    // QKV: 256x256 tile, 8 waves, 4-deep pipelined, grid 16*15=240
    k_gemm4<256, 256, 2, 4, 0, 1><<<240, 512, 0, stream>>>(hb, WqT, bqkv, qkvb, Vt, 4096, 3840, 1280);
    __bf16* attnb = hb;
    k_attn<<<256, 512, 0, stream>>>(qkvb, csb, snb, Vt, attnb);
    // proj: 128x128 tile, 4 waves, 4-deep pipelined, 2 blocks/CU, grid 32*10=320
    k_gemm4<128, 128, 2, 2, 1, 0><<<320, 256, 0, stream>>>(attnb, WpT, bproj, out, nullptr, 4096, 1280, 1280);
}

// Round 15
// 110.320 us; speedup vs baseline: 1.0187x; 1.0187x over previous
//
#include <hip/hip_runtime.h>
#include <hip/hip_bf16.h>

typedef __bf16 bf16x8 __attribute__((ext_vector_type(8)));
typedef __bf16 bf16x4 __attribute__((ext_vector_type(4)));
typedef float  f32x4  __attribute__((ext_vector_type(4)));
typedef float  f4v    __attribute__((ext_vector_type(4)));

#define DEV __device__ __forceinline__

DEV void gload16(void* lds, const void* g) {
    __builtin_amdgcn_global_load_lds((const __attribute__((address_space(1))) void*)g,
                                     (__attribute__((address_space(3))) void*)lds, 16, 0, 0);
}

#define VMCNT(n) asm volatile("s_waitcnt vmcnt(" #n ")" ::: "memory")
#define LGKM0()  asm volatile("s_waitcnt lgkmcnt(0)" ::: "memory")
#define BAR()    __builtin_amdgcn_s_barrier()
#define BARM()   asm volatile("s_barrier" ::: "memory")
#define SCHEDB() __builtin_amdgcn_sched_barrier(0)

// ---------------- fused prepass ----------------
__global__ __launch_bounds__(256) void k_prep(const float* __restrict__ hid, __bf16* __restrict__ hb,
                                              const float* __restrict__ Wqkv, __bf16* __restrict__ WqT,
                                              const float* __restrict__ Wproj, __bf16* __restrict__ WpT,
                                              const float* __restrict__ rcos, const float* __restrict__ rsin,
                                              __bf16* __restrict__ csb, __bf16* __restrict__ snb) {
    __shared__ float tile[64][65];
    const int b = blockIdx.x;
    const int tid = threadIdx.x;

    if (b < 5120) {
        int i = b * 256 + tid;
        f4v v = ((const f4v*)hid)[i];
        bf16x4 o;
        #pragma unroll
        for (int j = 0; j < 4; ++j) o[j] = (__bf16)v[j];
        ((bf16x4*)hb)[i] = o;
        return;
    }
    if (b < 5120 + 1200 + 400) {
        const float* in;
        __bf16* out;
        int R, C, bb, cb;
        if (b < 5120 + 1200) { in = Wqkv; out = WqT; R = 1280; C = 3840; cb = 60; bb = b - 5120; }
        else                 { in = Wproj; out = WpT; R = 1280; C = 1280; cb = 20; bb = b - 6320; }
        int br = (bb / cb) * 64, bc = (bb % cb) * 64;
        int tx = tid & 63, ty = tid >> 6;
        #pragma unroll
        for (int i = 0; i < 16; ++i) {
            int r = i * 4 + ty;
            tile[r][tx] = in[(size_t)(br + r) * C + (bc + tx)];
        }
        __syncthreads();
        #pragma unroll
        for (int i = 0; i < 16; ++i) {
            int r = i * 4 + ty;
            out[(size_t)(bc + r) * R + (br + tx)] = (__bf16)tile[tx][r];
        }
        return;
    }
    {
        int i = (b - 6720) * 256 + tid;
        f4v cv = ((const f4v*)rcos)[i];
        f4v sv = ((const f4v*)rsin)[i];
        bf16x4 co, so;
        #pragma unroll
        for (int j = 0; j < 4; ++j) { co[j] = (__bf16)cv[j]; so[j] = (__bf16)sv[j]; }
        ((bf16x4*)csb)[i] = co;
        ((bf16x4*)snb)[i] = so;
    }
}

// ---------------- 256x256 m201-style 8-phase GEMM, BK=64, dbuf, counted vmcnt(4) ----------------
// LDS (elems): offset(d, isB, half) = d*32768 + isB*16384 + half*8192; row-major [128][64].
// Swizzle: col ^= (row&7)<<3 on both stage source and ds_read (row pitch 128B).
// Waves: 8 = 2(wm) x 4(wn); wave tile 128x64; phase = one quadrant (mh,nh) x K=64 = 16 MFMA.
// Stage stagger: ph0/1 -> A halves(t1); ph2/3 -> B halves(t0+2); ph4/5 -> A(t0+2); ph6/7 -> B(t1+2).
// vmcnt(4) at ph3/ph7 (12 outstanding -> drain 8 = next tile), never 0 in steady loop.
__global__ __launch_bounds__(512, 2) void k_gemm256(const __bf16* __restrict__ A,
                                                    const __bf16* __restrict__ B,
                                                    const float* __restrict__ bias,
                                                    __bf16* __restrict__ C,
                                                    __bf16* __restrict__ Vt,
                                                    int M, int N, int K) {
    __shared__ __align__(16) __bf16 lds[65536];
    const int tid = threadIdx.x;
    const int lane = tid & 63, w = tid >> 6;
    const int wm = w >> 2, wn = w & 3;
    const int g = lane >> 4, fr = lane & 15;

    const int nbn = N >> 8;
    const int nwg = gridDim.x;
    int bid = blockIdx.x;
    {   // bijective XCD swizzle
        int q = nwg >> 3, r = nwg & 7;
        int xcd = bid & 7, o = bid >> 3;
        bid = (xcd < r ? xcd * (q + 1) : r * (q + 1) + (xcd - r) * q) + o;
    }
    const int bm = bid / nbn, bn = bid % nbn;
    const int brow = bm << 8, bcol = bn << 8;

    // staging: thread covers local row lr = tid>>3 (p=0) / +64 (p=1), src col pre-swizzled
    const int lr = tid >> 3;
    const int scg = ((tid & 7) ^ (lr & 7)) << 3;
    const __bf16* pA = A + (size_t)(brow + lr) * K + scg;
    const __bf16* pB = B + (size_t)(bcol + lr) * K + scg;
    __bf16* ldst = &lds[0] + tid * 8;

    // STAGE one half-tile: 2 gloads (p=0,1)
    #define STG(d, isB, half, kt)                                                              \
        {                                                                                      \
            const __bf16* _src = (isB) ? pB : pA;                                              \
            __bf16* _dst = ldst + (d) * 32768 + (isB) * 16384 + (half) * 8192;                 \
            gload16(_dst,        _src + (size_t)((half) * 128) * K + (kt) * 64);               \
            gload16(_dst + 4096, _src + (size_t)((half) * 128 + 64) * K + (kt) * 64);          \
        }

    const int NT = K >> 6;            // 20
    const int NITER = NT >> 1;        // 10
    f32x4 acc[8][4] = {};
    const int c0 = (g * 8) ^ ((fr & 7) << 3);
    const int c1 = c0 ^ 32;

    // A-frag reads: quadrant mh, kk pair
    auto rdA = [&](int d, int mh, bf16x8 (&a)[4][2]) {
        const __bf16* base = &lds[d * 32768 + wm * 8192 + (mh * 64 + fr) * 64];
        #pragma unroll
        for (int m = 0; m < 4; ++m) {
            a[m][0] = *(const bf16x8*)__builtin_assume_aligned(base + m * 1024 + c0, 16);
            a[m][1] = *(const bf16x8*)__builtin_assume_aligned(base + m * 1024 + c1, 16);
        }
    };
    // B-frag reads: quadrant nh
    auto rdB = [&](int d, int nh, bf16x8 (&b)[2][2]) {
        const __bf16* base = &lds[d * 32768 + 16384 + (wn >> 1) * 8192 + ((wn & 1) * 64 + nh * 32 + fr) * 64];
        #pragma unroll
        for (int n = 0; n < 2; ++n) {
            b[n][0] = *(const bf16x8*)__builtin_assume_aligned(base + n * 1024 + c0, 16);
            b[n][1] = *(const bf16x8*)__builtin_assume_aligned(base + n * 1024 + c1, 16);
        }
    };
    auto mfmaQ = [&](int mh, int nh, const bf16x8 (&a)[4][2], const bf16x8 (&b)[2][2]) {
        __builtin_amdgcn_s_setprio(1);
        #pragma unroll
        for (int m = 0; m < 4; ++m)
            #pragma unroll
            for (int n = 0; n < 2; ++n) {
                acc[mh * 4 + m][nh * 2 + n] = __builtin_amdgcn_mfma_f32_16x16x32_bf16(
                    a[m][0], b[n][0], acc[mh * 4 + m][nh * 2 + n], 0, 0, 0);
                acc[mh * 4 + m][nh * 2 + n] = __builtin_amdgcn_mfma_f32_16x16x32_bf16(
                    a[m][1], b[n][1], acc[mh * 4 + m][nh * 2 + n], 0, 0, 0);
            }
        __builtin_amdgcn_s_setprio(0);
    };

    // prologue: tile0 (8 loads) then B halves of tile1 (4 loads); vmcnt(4) drains tile0
    STG(0, 0, 0, 0); STG(0, 0, 1, 0); STG(0, 1, 0, 0); STG(0, 1, 1, 0);
    STG(1, 1, 0, 1); STG(1, 1, 1, 1);
    VMCNT(4);
    BARM();

    for (int it = 0; it < NITER; ++it) {
        const int t0 = 2 * it, t1 = t0 + 1;
        const bool s2 = (t0 + 2) < NT, s3 = (t1 + 2) < NT;
        bf16x8 a[4][2], bLo[2][2], bHi[2][2];

        // ---- tile t0 (dbuf 0) ----
        // ph0: reads A(mh0)+B(nh0); stage Alo(t1)
        rdA(0, 0, a); rdB(0, 0, bLo);
        STG(1, 0, 0, t1);
        BARM(); SCHEDB();
        mfmaQ(0, 0, a, bLo);
        BARM();
        // ph1: reads B(nh1); stage Ahi(t1)
        rdB(0, 1, bHi);
        STG(1, 0, 1, t1);
        BARM(); SCHEDB();
        mfmaQ(0, 1, a, bHi);
        BARM();
        // ph2: reads A(mh1); stage Blo(t0+2)
        rdA(0, 1, a);
        if (s2) STG(0, 1, 0, t0 + 2);
        BARM(); SCHEDB();
        mfmaQ(1, 1, a, bHi);
        BARM();
        // ph3: stage Bhi(t0+2); counted vmcnt certifies t1
        if (s2) { STG(0, 1, 1, t0 + 2); VMCNT(4); } else { VMCNT(0); }
        BARM(); SCHEDB();
        mfmaQ(1, 0, a, bLo);
        BARM();

        // ---- tile t1 (dbuf 1) ----
        // ph4: reads A(mh0)+B(nh0); stage Alo(t0+2)
        rdA(1, 0, a); rdB(1, 0, bLo);
        if (s2) STG(0, 0, 0, t0 + 2);
        BARM(); SCHEDB();
        mfmaQ(0, 0, a, bLo);
        BARM();
        // ph5: reads B(nh1); stage Ahi(t0+2)
        rdB(1, 1, bHi);
        if (s2) STG(0, 0, 1, t0 + 2);
        BARM(); SCHEDB();
        mfmaQ(0, 1, a, bHi);
        BARM();
        // ph6: reads A(mh1); stage Blo(t1+2)
        rdA(1, 1, a);
        if (s3) STG(1, 1, 0, t1 + 2);
        BARM(); SCHEDB();
        mfmaQ(1, 1, a, bHi);
        BARM();
        // ph7: stage Bhi(t1+2); counted vmcnt certifies t0+2
        if (s3) { STG(1, 1, 1, t1 + 2); VMCNT(4); } else { VMCNT(0); }
        BARM(); SCHEDB();
        mfmaQ(1, 0, a, bLo);
        BARM();
    }
    #undef STG

    // epilogue: acc[am][an] -> row = wm*128 + (am>>2)*64 + (am&3)*16 + g*4+j
    //                          col = wn*64 + (an>>1)*32 + (an&1)*16 + fr
    #pragma unroll
    for (int an = 0; an < 4; ++an) {
        const int col = bcol + wn * 64 + (an >> 1) * 32 + (an & 1) * 16 + fr;
        const float bv = bias[col];
        if (bcol >= 2560) {
            const int vcol = col - 2560;
            const int hh = vcol / 80;
            const int dd = vcol - hh * 80;
            __bf16* vp = Vt + (size_t)(hh * 80 + dd) * 4096 + brow + wm * 128 + g * 4;
            #pragma unroll
            for (int am = 0; am < 8; ++am) {
                bf16x4 pk;
                #pragma unroll
                for (int j = 0; j < 4; ++j) pk[j] = (__bf16)(acc[am][an][j] + bv);
                *(bf16x4*)(vp + ((am >> 2) * 64 + (am & 3) * 16)) = pk;
            }
        } else {
            #pragma unroll
            for (int am = 0; am < 8; ++am) {
                const int row = brow + wm * 128 + (am >> 2) * 64 + (am & 3) * 16 + g * 4;
                #pragma unroll
                for (int j = 0; j < 4; ++j)
                    C[(size_t)(row + j) * N + col] = (__bf16)(acc[am][an][j] + bv);
            }
        }
    }
}

// ---------------- TLP-pipelined GEMM template (proj), BK=32, dbuf ----------------
template<int BM, int BN, int WM, int WN, int OUTF32>
__global__ __launch_bounds__(WM * WN * 64, 4)
void k_gemm_t(const __bf16* __restrict__ A,
              const __bf16* __restrict__ B,
              const float* __restrict__ bias,
              void* __restrict__ Cp,
              int M, int N, int K) {
    constexpr int T   = WM * WN * 64;
    constexpr int WTM = BM / WM, WTN = BN / WN;
    constexpr int AM  = WTM / 16, AN = WTN / 16;
    constexpr int LR  = BM + BN;
    constexpr int BUFE = LR * 32;
    constexpr int LP  = (LR * 4) / T;
    static_assert((LR * 4) % T == 0 && (LP == 3 || LP == 4), "stage loads per thread");

    __shared__ __align__(16) __bf16 lds[2 * BUFE];
    const int tid = threadIdx.x;
    const int lane = tid & 63, w = tid >> 6;
    const int wm = w / WN, wn = w % WN;
    const int g = lane >> 4, fr = lane & 15;

    const int nbn = N / BN;
    const int nwg = gridDim.x;
    int bid = blockIdx.x;
    {
        int q = nwg >> 3, r = nwg & 7;
        int xcd = bid & 7, o = bid >> 3;
        bid = (xcd < r ? xcd * (q + 1) : r * (q + 1) + (xcd - r) * q) + o;
    }
    const int bm = bid / nbn, bn = bid % nbn;
    const int brow = bm * BM, bcol = bn * BN;

    const __bf16* gp[LP];
    #pragma unroll
    for (int p = 0; p < LP; ++p) {
        const int sp = (tid >> 2) + p * (T / 4);
        const int cg = ((tid & 3) ^ ((sp >> 1) & 3)) << 3;
        gp[p] = (sp < BM) ? (A + (size_t)(brow + sp) * K + cg)
                          : (B + (size_t)(bcol + (sp - BM)) * K + cg);
    }
    const int NT = K >> 5;

    #define STAGE(bufsel, kt)                                                   \
        {                                                                       \
            _Pragma("unroll")                                                   \
            for (int p = 0; p < LP; ++p)                                        \
                gload16(&lds[(bufsel) * BUFE + (p * T + tid) * 8], gp[p] + (kt) * 32); \
        }

    f32x4 acc[AM][AN] = {};

    STAGE(0, 0);
    STAGE(1, 1);
    if constexpr (LP == 3) { VMCNT(3); } else { VMCNT(4); }
    BAR();

    for (int t = 0; t < NT; ++t) {
        const __bf16* buf = &lds[(t & 1) * BUFE];
        bf16x8 a[AM], b[AN];
        #pragma unroll
        for (int m = 0; m < AM; ++m) {
            const int row = wm * WTM + m * 16 + fr;
            a[m] = *(const bf16x8*)__builtin_assume_aligned(
                &buf[row * 32 + ((g ^ ((row >> 1) & 3)) << 3)], 16);
        }
        #pragma unroll
        for (int n = 0; n < AN; ++n) {
            const int row = BM + wn * WTN + n * 16 + fr;
            b[n] = *(const bf16x8*)__builtin_assume_aligned(
                &buf[row * 32 + ((g ^ ((row >> 1) & 3)) << 3)], 16);
        }
        BAR();
        __builtin_amdgcn_s_setprio(1);
        #pragma unroll
        for (int m = 0; m < AM; ++m)
            #pragma unroll
            for (int n = 0; n < AN; ++n)
                acc[m][n] = __builtin_amdgcn_mfma_f32_16x16x32_bf16(a[m], b[n], acc[m][n], 0, 0, 0);
        __builtin_amdgcn_s_setprio(0);
        if (t + 2 < NT) { STAGE(t & 1, t + 2); if constexpr (LP == 3) { VMCNT(3); } else { VMCNT(4); } }
        else            { VMCNT(0); }
        BAR();
    }
    #undef STAGE

    #pragma unroll
    for (int n = 0; n < AN; ++n) {
        const int col = bcol + wn * WTN + n * 16 + fr;
        const float bv = bias[col];
        #pragma unroll
        for (int m = 0; m < AM; ++m) {
            const int row = brow + wm * WTM + m * 16 + g * 4;
            #pragma unroll
            for (int j = 0; j < 4; ++j) {
                float v = acc[m][n][j] + bv;
                if (OUTF32) ((float*)Cp)[(size_t)(row + j) * N + col] = v;
                else        ((__bf16*)Cp)[(size_t)(row + j) * N + col] = (__bf16)v;
            }
        }
    }
}

// ---------------- flash attention: QBLK=256, dbuf + async reg-stage, FUSED K-RoPE, in-reg L ----------------
__global__ __launch_bounds__(512, 2) void k_attn(const __bf16* __restrict__ qkv,
                                                 const __bf16* __restrict__ csb,
                                                 const __bf16* __restrict__ snb,
                                                 const __bf16* __restrict__ Vt,
                                                 __bf16* __restrict__ Ao) {
    __shared__ __align__(16) __bf16 Ks[2][3 * 2048];
    __shared__ __align__(16) __bf16 Vs[2][96 * 64];
    __shared__ __align__(16) __bf16 Pl[8 * 1024];

    const int blk = blockIdx.x;
    const int seg = blk & 7;
    const int qt = (blk >> 3) & 1;
    const int h = blk >> 4;
    const int tid = threadIdx.x;
    const int w = tid >> 6, lane = tid & 63;
    const int g = lane >> 4, fr = lane & 15;
    const int qrow0 = seg * 512 + qt * 256 + w * 32;
    const float qscale = 0.111803398875f * 1.44269504089f; // rsqrt(80) * log2(e)

    const int krow = tid / 5, ksl = tid - krow * 5;   // valid when tid < 320
    const int kd = ksl * 8;
    const int vd0 = tid >> 3, vc0 = (tid & 7) << 3;
    const int vd1 = 64 + (tid >> 3);
    const __bf16* kqbase = qkv + 1280 + h * 80;
    const __bf16* vbase = Vt + (size_t)h * 80 * 4096;

    bf16x8 kx1, kx2, kcs, ksn, vA, vB;
    {
        const int s = seg * 512 + krow;
        if (tid < 320) {
            kx1 = *(const bf16x8*)(kqbase + (size_t)s * 3840 + kd);
            kx2 = *(const bf16x8*)(kqbase + (size_t)s * 3840 + kd + 40);
            kcs = *(const bf16x8*)(csb + s * 40 + kd);
            ksn = *(const bf16x8*)(snb + s * 40 + kd);
        }
        const int t0 = seg * 512;
        vA = *(const bf16x8*)(vbase + (size_t)vd0 * 4096 + t0 + vc0);
        if (tid < 128) vB = *(const bf16x8*)(vbase + (size_t)vd1 * 4096 + t0 + vc0);
    }
    SCHEDB();

    bf16x8 aq[2][3];
    #pragma unroll
    for (int rg = 0; rg < 2; ++rg) {
        const int s = qrow0 + rg * 16 + fr;
        const __bf16* qrow = qkv + (size_t)s * 3840 + h * 80;
        const __bf16* cr = csb + s * 40;
        const __bf16* sr2 = snb + s * 40;
        #pragma unroll
        for (int ks = 0; ks < 3; ++ks) {
            const int cc0 = ks * 32 + g * 8;
            bf16x8 v;
            if (cc0 < 80) {
                const int lo = (cc0 < 40) ? 1 : 0;
                const int d0 = lo ? cc0 : cc0 - 40;
                bf16x8 x = *(const bf16x8*)(qrow + cc0);
                bf16x8 y = *(const bf16x8*)(qrow + (lo ? cc0 + 40 : cc0 - 40));
                bf16x8 cv = *(const bf16x8*)(cr + d0);
                bf16x8 sv = *(const bf16x8*)(sr2 + d0);
                #pragma unroll
                for (int j = 0; j < 8; ++j) {
                    float xf = (float)x[j], yf = (float)y[j];
                    float cf = (float)cv[j], sf = (float)sv[j];
                    float r = lo ? (xf * cf - yf * sf) : (xf * cf + yf * sf);
                    v[j] = (__bf16)(r * qscale);
                }
            } else {
                #pragma unroll
                for (int j = 0; j < 8; ++j) v[j] = (__bf16)0.f;
            }
            aq[rg][ks] = v;
        }
    }

    if (tid < 256) {
        const int buf = tid >> 7;
        const int rr = (tid >> 1) & 63;
        const int cc = 80 + ((tid & 1) << 3);
        bf16x8 z;
        #pragma unroll
        for (int j = 0; j < 8; ++j) z[j] = (__bf16)0.f;
        *(bf16x8*)&Ks[buf][2 * 2048 + rr * 32 + ((cc & 31) ^ ((rr & 3) << 3))] = z;
    }

    f32x4 o[2][5] = {};
    float Lacc[2] = {0.f, 0.f};
    __bf16* pw = &Pl[w * 1024];

    for (int tc = 0; tc < 8; ++tc) {
        const int p = tc & 1;

        VMCNT(0);
        if (tid < 320) {
            bf16x8 o1, o2;
            #pragma unroll
            for (int j = 0; j < 8; ++j) {
                float x1 = (float)kx1[j], x2 = (float)kx2[j];
                float cf = (float)kcs[j], sf = (float)ksn[j];
                o1[j] = (__bf16)(x1 * cf - x2 * sf);
                o2[j] = (__bf16)(x2 * cf + x1 * sf);
            }
            const int c1 = kd, c2 = kd + 40;
            *(bf16x8*)&Ks[p][(c1 >> 5) * 2048 + krow * 32 + ((c1 & 31) ^ ((krow & 3) << 3))] = o1;
            *(bf16x8*)&Ks[p][(c2 >> 5) * 2048 + krow * 32 + ((c2 & 31) ^ ((krow & 3) << 3))] = o2;
        }
        *(bf16x8*)&Vs[p][vd0 * 64 + (vc0 ^ ((vd0 & 7) << 3))] = vA;
        if (tid < 128) *(bf16x8*)&Vs[p][vd1 * 64 + (vc0 ^ ((vd1 & 7) << 3))] = vB;
        LGKM0();
        BAR();

        if (tc + 1 < 8) {
            const int t1 = seg * 512 + (tc + 1) * 64;
            if (tid < 320) {
                const int s = t1 + krow;
                kx1 = *(const bf16x8*)(kqbase + (size_t)s * 3840 + kd);
                kx2 = *(const bf16x8*)(kqbase + (size_t)s * 3840 + kd + 40);
                kcs = *(const bf16x8*)(csb + s * 40 + kd);
                ksn = *(const bf16x8*)(snb + s * 40 + kd);
            }
            vA = *(const bf16x8*)(vbase + (size_t)vd0 * 4096 + t1 + vc0);
            if (tid < 128) vB = *(const bf16x8*)(vbase + (size_t)vd1 * 4096 + t1 + vc0);
            SCHEDB();
        }

        #pragma unroll
        for (int rg = 0; rg < 2; ++rg) {
            f32x4 sacc[4] = {};
            #pragma unroll
            for (int ks = 0; ks < 3; ++ks) {
                #pragma unroll
                for (int n = 0; n < 4; ++n) {
                    bf16x8 bk = *(const bf16x8*)&Ks[p][ks * 2048 + (n * 16 + fr) * 32 + ((g * 8) ^ ((fr & 3) << 3))];
                    sacc[n] = __builtin_amdgcn_mfma_f32_16x16x32_bf16(bk, aq[rg][ks], sacc[n], 0, 0, 0);
                }
            }

            float pv[4][4];
            float rs = 0.f;
            #pragma unroll
            for (int n = 0; n < 4; ++n)
                #pragma unroll
                for (int j = 0; j < 4; ++j) {
                    float e = exp2f(sacc[n][j]);
                    pv[n][j] = e;
                    rs += e;
                }
            rs += __shfl_xor(rs, 16);
            rs += __shfl_xor(rs, 32);
            Lacc[rg] += rs;

            #pragma unroll
            for (int n = 0; n < 4; ++n) {
                bf16x4 pk;
                #pragma unroll
                for (int j = 0; j < 4; ++j) pk[j] = (__bf16)pv[n][j];
                int col = (n * 16 + g * 4) ^ ((fr & 7) << 3);
                *(bf16x4*)&pw[fr * 64 + col] = pk;
            }

            #pragma unroll
            for (int ks2 = 0; ks2 < 2; ++ks2) {
                bf16x8 pa = *(const bf16x8*)&pw[fr * 64 + (((ks2 * 32) + g * 8) ^ ((fr & 7) << 3))];
                #pragma unroll
                for (int dt = 0; dt < 5; ++dt) {
                    bf16x8 bv = *(const bf16x8*)&Vs[p][(dt * 16 + fr) * 64 + (((ks2 * 32) + g * 8) ^ ((fr & 7) << 3))];
                    o[rg][dt] = __builtin_amdgcn_mfma_f32_16x16x32_bf16(pa, bv, o[rg][dt], 0, 0, 0);
                }
            }
        }
    }

    #pragma unroll
    for (int rg = 0; rg < 2; ++rg) {
        float invj[4];
        #pragma unroll
        for (int j = 0; j < 4; ++j)
            invj[j] = 1.0f / __shfl(Lacc[rg], g * 4 + j);
        #pragma unroll
        for (int dt = 0; dt < 5; ++dt)
            #pragma unroll
            for (int j = 0; j < 4; ++j)
                Ao[(size_t)(qrow0 + rg * 16 + g * 4 + j) * 1280 + h * 80 + dt * 16 + fr] =
                    (__bf16)(o[rg][dt][j] * invj[j]);
    }
}

extern "C" void kernel_launch(void* const* d_in, const int* in_sizes, int n_in,
                              void* d_out, int out_size, void* d_ws, size_t ws_size,
                              hipStream_t stream) {
    const float* hid   = (const float*)d_in[0];
    const float* rcos  = (const float*)d_in[3];
    const float* rsin  = (const float*)d_in[4];
    const float* Wqkv  = (const float*)d_in[5];
    const float* bqkv  = (const float*)d_in[6];
    const float* Wproj = (const float*)d_in[7];
    const float* bproj = (const float*)d_in[8];
    float* out = (float*)d_out;

    char* ws = (char*)d_ws;
    size_t off = 0;
    auto carve = [&](size_t bytes) -> char* {
        char* p = ws + off;
        off += (bytes + 255) & ~(size_t)255;
        return p;
    };
    __bf16* hb   = (__bf16*)carve((size_t)4096 * 1280 * 2); // later reused as attn output
    __bf16* WqT  = (__bf16*)carve((size_t)3840 * 1280 * 2);
    __bf16* WpT  = (__bf16*)carve((size_t)1280 * 1280 * 2);
    __bf16* qkvb = (__bf16*)carve((size_t)4096 * 3840 * 2);
    __bf16* Vt   = (__bf16*)carve((size_t)16 * 80 * 4096 * 2);
    __bf16* csb  = (__bf16*)carve((size_t)4096 * 40 * 2);
    __bf16* snb  = (__bf16*)carve((size_t)4096 * 40 * 2);

    k_prep<<<6880, 256, 0, stream>>>(hid, hb, Wqkv, WqT, Wproj, WpT, rcos, rsin, csb, snb);
    k_gemm256<<<240, 512, 0, stream>>>(hb, WqT, bqkv, qkvb, Vt, 4096, 3840, 1280);
    __bf16* attnb = hb;
    k_attn<<<256, 512, 0, stream>>>(qkvb, csb, snb, Vt, attnb);
    k_gemm_t<128, 128, 2, 2, 1><<<320, 256, 0, stream>>>(attnb, WpT, bproj, out, 4096, 1280, 1280);
}